// Round 1
// baseline (296.123 us; speedup 1.0000x reference)
//
#include <hip/hip_runtime.h>

#define BH 64
#define S_ 4096
#define D_ 128
#define SPLITK 8
#define SCHUNK (S_ / SPLITK)   // 512
#define SCALE 0.25f            // 1/sqrt(n_heads=16)

// ---------------------------------------------------------------------------
// Phase A: partial[ks][bh][d][e] = sum_{s in chunk ks} q[bh][s][d]*k[bh][s][e]
// (scaled). 128x128 output tile per block, 256 threads, 8x8 per thread.
// Both operands are contraction-major in memory (q[s][d], k[s][e]) -> tiles
// load fully coalesced, fragments read as float4 from LDS rows.
// ---------------------------------------------------------------------------
template <bool ATOMIC>
__global__ __launch_bounds__(256) void qk_kernel(const float* __restrict__ q,
                                                 const float* __restrict__ k,
                                                 float* __restrict__ part) {
  const int bh = blockIdx.x;
  const int ks = blockIdx.y;
  const float* __restrict__ qb = q + (size_t)bh * S_ * D_;
  const float* __restrict__ kb = k + (size_t)bh * S_ * D_;

  __shared__ float Qt[32][D_];
  __shared__ float Kt[32][D_];

  const int tid = threadIdx.x;
  const int tx = tid & 15, ty = tid >> 4;

  float acc[8][8];
#pragma unroll
  for (int i = 0; i < 8; ++i)
#pragma unroll
    for (int j = 0; j < 8; ++j) acc[i][j] = 0.f;

  const int s0 = ks * SCHUNK;
  for (int st = 0; st < SCHUNK; st += 32) {
#pragma unroll
    for (int i = 0; i < 4; ++i) {
      const int idx4 = tid + i * 256;       // 0..1023 float4 slots
      const int row  = idx4 >> 5;           // 32 float4 per 128-float row
      const int col  = (idx4 & 31) << 2;
      const size_t goff = (size_t)(s0 + st + row) * D_ + col;
      *(float4*)&Qt[row][col] = *(const float4*)(qb + goff);
      *(float4*)&Kt[row][col] = *(const float4*)(kb + goff);
    }
    __syncthreads();
#pragma unroll
    for (int s = 0; s < 32; ++s) {
      float a[8], b[8];
      *(float4*)&a[0] = *(const float4*)&Qt[s][ty * 8];
      *(float4*)&a[4] = *(const float4*)&Qt[s][ty * 8 + 4];
      *(float4*)&b[0] = *(const float4*)&Kt[s][tx * 8];
      *(float4*)&b[4] = *(const float4*)&Kt[s][tx * 8 + 4];
#pragma unroll
      for (int i = 0; i < 8; ++i)
#pragma unroll
        for (int j = 0; j < 8; ++j) acc[i][j] = fmaf(a[i], b[j], acc[i][j]);
    }
    __syncthreads();
  }

  if (ATOMIC) {
    float* dst = part + (size_t)bh * D_ * D_;
#pragma unroll
    for (int i = 0; i < 8; ++i) {
      const int d = ty * 8 + i;
#pragma unroll
      for (int j = 0; j < 8; ++j)
        atomicAdd(dst + (size_t)d * D_ + tx * 8 + j, acc[i][j] * SCALE);
    }
  } else {
    float* dst = part + ((size_t)ks * BH + bh) * D_ * D_;
#pragma unroll
    for (int i = 0; i < 8; ++i) {
      const int d = ty * 8 + i;
      float4 r0 = make_float4(acc[i][0] * SCALE, acc[i][1] * SCALE,
                              acc[i][2] * SCALE, acc[i][3] * SCALE);
      float4 r1 = make_float4(acc[i][4] * SCALE, acc[i][5] * SCALE,
                              acc[i][6] * SCALE, acc[i][7] * SCALE);
      *(float4*)(dst + (size_t)d * D_ + tx * 8) = r0;
      *(float4*)(dst + (size_t)d * D_ + tx * 8 + 4) = r1;
    }
  }
}

// ---------------------------------------------------------------------------
// Phase B: combine split-K partials + row softmax. P written in place into
// partial slot 0 (reads of a row complete before its write; rows are
// wave-private). One wave per 8 rows, lanes cover the 128 columns (2 each).
// ---------------------------------------------------------------------------
__global__ __launch_bounds__(256) void softmax_kernel(float* __restrict__ buf,
                                                      int nks) {
  const int bh = blockIdx.x;
  const int wv = threadIdx.x >> 6;
  const int lane = threadIdx.x & 63;
  const size_t kstride = (size_t)BH * D_ * D_;
  float* base = buf + (size_t)bh * D_ * D_;
  const int d0 = blockIdx.y * 32 + wv * 8;
  for (int d = d0; d < d0 + 8; ++d) {
    float v0 = 0.f, v1 = 0.f;
    for (int ks = 0; ks < nks; ++ks) {
      const float* row = base + ks * kstride + (size_t)d * D_;
      v0 += row[lane];
      v1 += row[lane + 64];
    }
    float m = fmaxf(v0, v1);
#pragma unroll
    for (int off = 32; off; off >>= 1) m = fmaxf(m, __shfl_xor(m, off, 64));
    const float e0 = __expf(v0 - m), e1 = __expf(v1 - m);
    float sum = e0 + e1;
#pragma unroll
    for (int off = 32; off; off >>= 1) sum += __shfl_xor(sum, off, 64);
    const float inv = 1.f / sum;
    base[(size_t)d * D_ + lane] = e0 * inv;
    base[(size_t)d * D_ + lane + 64] = e1 * inv;
  }
}

// ---------------------------------------------------------------------------
// Phase C: out[bh][d][s] = sum_e P[bh][d][e] * v[bh][s][e].
// 128(d) x 128(s) tile per block; stage P and V transposed (contraction-major)
// in LDS so fragments are float4 reads; coalesced global loads along e.
// ---------------------------------------------------------------------------
__global__ __launch_bounds__(256) void pv_kernel(const float* __restrict__ P,
                                                 const float* __restrict__ v,
                                                 float* __restrict__ out) {
  const int bh = blockIdx.x;
  const int s0 = blockIdx.y * 128;
  const float* __restrict__ Pb = P + (size_t)bh * D_ * D_;
  const float* __restrict__ vb = v + (size_t)bh * S_ * D_;

  __shared__ float Pt[32][D_];  // Pt[e_local][d]
  __shared__ float Vt[32][D_];  // Vt[e_local][s_local]

  const int tid = threadIdx.x;
  const int tx = tid & 15, ty = tid >> 4;

  float acc[8][8];
#pragma unroll
  for (int i = 0; i < 8; ++i)
#pragma unroll
    for (int j = 0; j < 8; ++j) acc[i][j] = 0.f;

  for (int e0 = 0; e0 < D_; e0 += 32) {
#pragma unroll
    for (int i = 0; i < 4; ++i) {
      const int idx4 = tid + i * 256;   // 0..1023
      const int r  = idx4 >> 3;         // row (d or s_local), 8 float4 per row
      const int c4 = idx4 & 7;          // float4 index within 32 e's
      float4 p4 = *(const float4*)(Pb + (size_t)r * D_ + e0 + c4 * 4);
      Pt[c4 * 4 + 0][r] = p4.x;
      Pt[c4 * 4 + 1][r] = p4.y;
      Pt[c4 * 4 + 2][r] = p4.z;
      Pt[c4 * 4 + 3][r] = p4.w;
      float4 v4 = *(const float4*)(vb + (size_t)(s0 + r) * D_ + e0 + c4 * 4);
      Vt[c4 * 4 + 0][r] = v4.x;
      Vt[c4 * 4 + 1][r] = v4.y;
      Vt[c4 * 4 + 2][r] = v4.z;
      Vt[c4 * 4 + 3][r] = v4.w;
    }
    __syncthreads();
#pragma unroll
    for (int ec = 0; ec < 32; ++ec) {
      float a[8], b[8];
      *(float4*)&a[0] = *(const float4*)&Pt[ec][ty * 8];
      *(float4*)&a[4] = *(const float4*)&Pt[ec][ty * 8 + 4];
      *(float4*)&b[0] = *(const float4*)&Vt[ec][tx * 8];
      *(float4*)&b[4] = *(const float4*)&Vt[ec][tx * 8 + 4];
#pragma unroll
      for (int i = 0; i < 8; ++i)
#pragma unroll
        for (int j = 0; j < 8; ++j) acc[i][j] = fmaf(a[i], b[j], acc[i][j]);
    }
    __syncthreads();
  }

  float* ob = out + (size_t)bh * D_ * S_;
#pragma unroll
  for (int i = 0; i < 8; ++i) {
    const int d = ty * 8 + i;
    float4 r0 = make_float4(acc[i][0], acc[i][1], acc[i][2], acc[i][3]);
    float4 r1 = make_float4(acc[i][4], acc[i][5], acc[i][6], acc[i][7]);
    *(float4*)(ob + (size_t)d * S_ + s0 + tx * 8) = r0;
    *(float4*)(ob + (size_t)d * S_ + s0 + tx * 8 + 4) = r1;
  }
}

extern "C" void kernel_launch(void* const* d_in, const int* in_sizes, int n_in,
                              void* d_out, int out_size, void* d_ws,
                              size_t ws_size, hipStream_t stream) {
  const float* q = (const float*)d_in[0];
  const float* k = (const float*)d_in[1];
  const float* v = (const float*)d_in[2];
  float* out = (float*)d_out;
  float* ws = (float*)d_ws;

  const size_t need_split = (size_t)SPLITK * BH * D_ * D_ * sizeof(float);
  if (ws_size >= need_split) {
    // Deterministic split-K partials.
    qk_kernel<false><<<dim3(BH, SPLITK), 256, 0, stream>>>(q, k, ws);
    softmax_kernel<<<dim3(BH, 4), 256, 0, stream>>>(ws, SPLITK);
  } else {
    // Fallback: atomic accumulation into a single 4 MiB score buffer.
    hipMemsetAsync(d_ws, 0, (size_t)BH * D_ * D_ * sizeof(float), stream);
    qk_kernel<true><<<dim3(BH, SPLITK), 256, 0, stream>>>(q, k, ws);
    softmax_kernel<<<dim3(BH, 4), 256, 0, stream>>>(ws, 1);
  }
  pv_kernel<<<dim3(BH, S_ / 128), 256, 0, stream>>>(ws, v, out);
}

// Round 2
// 157.535 us; speedup vs baseline: 1.8797x; 1.8797x over previous
//
#include <hip/hip_runtime.h>

#define BH 64
#define S_ 4096
#define D_ 128
#define SCALE 0.25f  // 1/sqrt(n_heads=16)

typedef __attribute__((ext_vector_type(4))) short short4v;
typedef __attribute__((ext_vector_type(8))) short short8v;
typedef __attribute__((ext_vector_type(4))) float f32x4;

__device__ inline unsigned short f2bf(float x) {
  union { float f; unsigned u; } v; v.f = x;
  unsigned r = v.u + 0x7fff + ((v.u >> 16) & 1);
  return (unsigned short)(r >> 16);
}
__device__ inline float bf2f(unsigned short h) {
  union { float f; unsigned u; } v; v.u = ((unsigned)h) << 16; return v.f;
}
__device__ inline short8v cat8(short4v a, short4v b) {
  short8v r;
  r[0] = a[0]; r[1] = a[1]; r[2] = a[2]; r[3] = a[3];
  r[4] = b[0]; r[5] = b[1]; r[6] = b[2]; r[7] = b[3];
  return r;
}
// Hardware transpose read: lane l, elem j <- M[base_row + (l>>4)*4 + j][ctile + (l&15)]
// when lane l's addr points at M[base_row + (l>>4)*4 + ((l&15)>>2)][ctile + (l&3)*4].
__device__ inline short4v tr16(unsigned addr) {
  short4v r;
  asm volatile("ds_read_b64_tr_b16 %0, %1" : "=v"(r) : "v"(addr));
  return r;
}

// ---------------------------------------------------------------------------
// Phase A: split-K QK^T with split-bf16 (hi/lo) MFMA.
// part[ks][bh][d][e] = SCALE * sum_{s in chunk} q[s][d]*k[s][e]
// LDS tiles: 4 x [32 s][136 d] bf16 (padded rows, 272B stride) : Qhi Qlo Khi Klo
// ---------------------------------------------------------------------------
#define TILE_SH 4352   // 32*136 shorts per tile
#define ROW_B 272      // bytes per LDS row

template <int NKS, bool ATOMIC>
__global__ __launch_bounds__(256) void qk_mfma(const float* __restrict__ q,
                                               const float* __restrict__ k,
                                               float* __restrict__ part) {
  const int bh = blockIdx.x;
  const int ks = blockIdx.y;
  const int schunk = S_ / NKS;
  const float* qb = q + (size_t)bh * S_ * D_ + (size_t)ks * schunk * D_;
  const float* kb = k + (size_t)bh * S_ * D_ + (size_t)ks * schunk * D_;

  __shared__ alignas(16) short lds[4 * TILE_SH];
  const unsigned base_u = (unsigned)(uintptr_t)&lds[0];

  const int tid = threadIdx.x;
  const int wv = tid >> 6, lane = tid & 63;

  f32x4 acc[8][2];
#pragma unroll
  for (int i = 0; i < 8; ++i)
#pragma unroll
    for (int j = 0; j < 2; ++j) acc[i][j] = (f32x4){0.f, 0.f, 0.f, 0.f};

  // tr-read per-lane address base (row within k-half, col-group)
  const int lrow = ((lane >> 4) << 2) + ((lane & 15) >> 2);
  const unsigned trbase = base_u + (unsigned)lrow * ROW_B + (unsigned)(lane & 3) * 8;
  const unsigned aQ = trbase;                 // Qhi tile 0, Qlo tile 1
  const unsigned aK = trbase + 2u * TILE_SH * 2;  // Khi tile 2, Klo tile 3

  float4 qr[4], kr[4];
  const int nsteps = schunk / 32;

  // prologue load step 0
#pragma unroll
  for (int i = 0; i < 4; ++i) {
    int idx4 = tid + i * 256;
    size_t off = (size_t)(idx4 >> 5) * D_ + (idx4 & 31) * 4;
    qr[i] = *(const float4*)(qb + off);
    kr[i] = *(const float4*)(kb + off);
  }

  for (int st = 0; st < nsteps; ++st) {
    __syncthreads();
    // store tiles (fp32 -> bf16 hi/lo)
#pragma unroll
    for (int i = 0; i < 4; ++i) {
      int idx4 = tid + i * 256;
      int row = idx4 >> 5, c4 = idx4 & 31;
      int off = row * 136 + c4 * 4;  // shorts
      float4 xq = qr[i], xk = kr[i];
      short4v qh, ql, kh, kl;
      {
        float f0 = xq.x, f1 = xq.y, f2 = xq.z, f3 = xq.w;
        unsigned short h0 = f2bf(f0), h1 = f2bf(f1), h2 = f2bf(f2), h3 = f2bf(f3);
        qh[0] = (short)h0; qh[1] = (short)h1; qh[2] = (short)h2; qh[3] = (short)h3;
        ql[0] = (short)f2bf(f0 - bf2f(h0)); ql[1] = (short)f2bf(f1 - bf2f(h1));
        ql[2] = (short)f2bf(f2 - bf2f(h2)); ql[3] = (short)f2bf(f3 - bf2f(h3));
      }
      {
        float f0 = xk.x, f1 = xk.y, f2 = xk.z, f3 = xk.w;
        unsigned short h0 = f2bf(f0), h1 = f2bf(f1), h2 = f2bf(f2), h3 = f2bf(f3);
        kh[0] = (short)h0; kh[1] = (short)h1; kh[2] = (short)h2; kh[3] = (short)h3;
        kl[0] = (short)f2bf(f0 - bf2f(h0)); kl[1] = (short)f2bf(f1 - bf2f(h1));
        kl[2] = (short)f2bf(f2 - bf2f(h2)); kl[3] = (short)f2bf(f3 - bf2f(h3));
      }
      *(short4v*)&lds[off] = qh;
      *(short4v*)&lds[off + TILE_SH] = ql;
      *(short4v*)&lds[off + 2 * TILE_SH] = kh;
      *(short4v*)&lds[off + 3 * TILE_SH] = kl;
    }
    __syncthreads();

    // prefetch next step's globals (hidden under MFMA)
    if (st + 1 < nsteps) {
#pragma unroll
      for (int i = 0; i < 4; ++i) {
        int idx4 = tid + i * 256;
        size_t off = (size_t)((st + 1) * 32 + (idx4 >> 5)) * D_ + (idx4 & 31) * 4;
        qr[i] = *(const float4*)(qb + off);
        kr[i] = *(const float4*)(kb + off);
      }
    }

    // B fragments (wave's 2 n-tiles, hi/lo, 2 k-halves): 8 tr reads
    short4v bf[2][2][2];
#pragma unroll
    for (int nl = 0; nl < 2; ++nl) {
      unsigned cb = (unsigned)(wv * 2 + nl) * 32;
#pragma unroll
      for (int ver = 0; ver < 2; ++ver)
#pragma unroll
        for (int kh2 = 0; kh2 < 2; ++kh2)
          bf[nl][ver][kh2] = tr16(aK + ver * (TILE_SH * 2) + kh2 * (16 * ROW_B) + cb);
    }
    // A fragment double buffer over m-tiles
    short4v af[2][2][2];
#pragma unroll
    for (int ver = 0; ver < 2; ++ver)
#pragma unroll
      for (int kh2 = 0; kh2 < 2; ++kh2)
        af[0][ver][kh2] = tr16(aQ + ver * (TILE_SH * 2) + kh2 * (16 * ROW_B));

#pragma unroll
    for (int mt = 0; mt < 8; ++mt) {
      if (mt < 7) {
        unsigned cb = (unsigned)(mt + 1) * 32;
#pragma unroll
        for (int ver = 0; ver < 2; ++ver)
#pragma unroll
          for (int kh2 = 0; kh2 < 2; ++kh2)
            af[(mt + 1) & 1][ver][kh2] =
                tr16(aQ + ver * (TILE_SH * 2) + kh2 * (16 * ROW_B) + cb);
        asm volatile("s_waitcnt lgkmcnt(4)" ::: "memory");
      } else {
        asm volatile("s_waitcnt lgkmcnt(0)" ::: "memory");
      }
      __builtin_amdgcn_sched_barrier(0);
      short8v ah = cat8(af[mt & 1][0][0], af[mt & 1][0][1]);
      short8v al = cat8(af[mt & 1][1][0], af[mt & 1][1][1]);
#pragma unroll
      for (int nl = 0; nl < 2; ++nl) {
        short8v bh_ = cat8(bf[nl][0][0], bf[nl][0][1]);
        short8v bl_ = cat8(bf[nl][1][0], bf[nl][1][1]);
        acc[mt][nl] = __builtin_amdgcn_mfma_f32_16x16x32_bf16(ah, bh_, acc[mt][nl], 0, 0, 0);
        acc[mt][nl] = __builtin_amdgcn_mfma_f32_16x16x32_bf16(ah, bl_, acc[mt][nl], 0, 0, 0);
        acc[mt][nl] = __builtin_amdgcn_mfma_f32_16x16x32_bf16(al, bh_, acc[mt][nl], 0, 0, 0);
      }
    }
  }

  // epilogue: D layout col=lane&15, row=(lane>>4)*4+reg
  if (!ATOMIC) {
    float* dst = part + ((size_t)ks * BH + bh) * D_ * D_;
#pragma unroll
    for (int mt = 0; mt < 8; ++mt)
#pragma unroll
      for (int nl = 0; nl < 2; ++nl) {
        int e = (wv * 2 + nl) * 16 + (lane & 15);
#pragma unroll
        for (int r = 0; r < 4; ++r) {
          int d = mt * 16 + ((lane >> 4) << 2) + r;
          dst[(size_t)d * D_ + e] = acc[mt][nl][r] * SCALE;
        }
      }
  } else {
    float* dst = part + (size_t)bh * D_ * D_;
#pragma unroll
    for (int mt = 0; mt < 8; ++mt)
#pragma unroll
      for (int nl = 0; nl < 2; ++nl) {
        int e = (wv * 2 + nl) * 16 + (lane & 15);
#pragma unroll
        for (int r = 0; r < 4; ++r) {
          int d = mt * 16 + ((lane >> 4) << 2) + r;
          atomicAdd(&dst[(size_t)d * D_ + e], acc[mt][nl][r] * SCALE);
        }
      }
  }
}

// ---------------------------------------------------------------------------
// Phase B: combine partials + row softmax -> P as bf16 (linear [d][e] layout)
// ---------------------------------------------------------------------------
template <int NKS>
__global__ __launch_bounds__(256) void softmax_k(const float* __restrict__ part,
                                                 short* __restrict__ Pg) {
  const int bh = blockIdx.x;
  const int wv = threadIdx.x >> 6, lane = threadIdx.x & 63;
  const size_t kstride = (size_t)BH * D_ * D_;
  const float* base = part + (size_t)bh * D_ * D_;
  short* dst = Pg + (size_t)bh * D_ * D_;
#pragma unroll
  for (int i = 0; i < 8; ++i) {
    int d = blockIdx.y * 32 + wv * 8 + i;
    float v0 = 0.f, v1 = 0.f;
    for (int ks2 = 0; ks2 < NKS; ++ks2) {
      const float* row = base + ks2 * kstride + (size_t)d * D_;
      v0 += row[lane];
      v1 += row[lane + 64];
    }
    float m = fmaxf(v0, v1);
#pragma unroll
    for (int off = 32; off; off >>= 1) m = fmaxf(m, __shfl_xor(m, off, 64));
    float e0 = __expf(v0 - m), e1 = __expf(v1 - m);
    float s = e0 + e1;
#pragma unroll
    for (int off = 32; off; off >>= 1) s += __shfl_xor(s, off, 64);
    float inv = 1.f / s;
    dst[(size_t)d * D_ + lane] = (short)f2bf(e0 * inv);
    dst[(size_t)d * D_ + lane + 64] = (short)f2bf(e1 * inv);
  }
}

// ---------------------------------------------------------------------------
// Phase C: out[d][s] = sum_e P[d][e] * v[s][e] — bf16 MFMA, contraction over
// the contiguous e axis (no transposes). P padded to 136-short rows in LDS.
// ---------------------------------------------------------------------------
__global__ __launch_bounds__(256) void pv_mfma(const short* __restrict__ Pg,
                                               const float* __restrict__ v,
                                               float* __restrict__ out) {
  const int bh = blockIdx.x;
  const int s0 = blockIdx.y * 128;
  const float* vb = v + (size_t)bh * S_ * D_;
  __shared__ alignas(16) short P_lds[128 * 136];
  __shared__ alignas(16) short V_lds[128 * 36];
  const int tid = threadIdx.x;
  const int wv = tid >> 6, lane = tid & 63;

  // stage P (bf16, rows padded 128->136)
  const short* Pb = Pg + (size_t)bh * D_ * D_;
#pragma unroll
  for (int i = 0; i < 8; ++i) {
    int idx8 = tid + i * 256;
    int row = idx8 >> 4, c8 = idx8 & 15;
    short8v val = *(const short8v*)(Pb + row * 128 + c8 * 8);
    *(short8v*)(P_lds + row * 136 + c8 * 8) = val;
  }

  f32x4 acc[8][2];
#pragma unroll
  for (int i = 0; i < 8; ++i)
#pragma unroll
    for (int j = 0; j < 2; ++j) acc[i][j] = (f32x4){0.f, 0.f, 0.f, 0.f};

#pragma unroll
  for (int es = 0; es < 4; ++es) {
    __syncthreads();
    // stage V chunk [128 s][32 e] bf16, rows padded to 36 shorts
#pragma unroll
    for (int i = 0; i < 4; ++i) {
      int idx4 = tid + i * 256;
      int s = idx4 >> 3, c4 = idx4 & 7;
      float4 x = *(const float4*)(vb + (size_t)(s0 + s) * D_ + es * 32 + c4 * 4);
      short4v h;
      h[0] = (short)f2bf(x.x); h[1] = (short)f2bf(x.y);
      h[2] = (short)f2bf(x.z); h[3] = (short)f2bf(x.w);
      *(short4v*)(V_lds + s * 36 + c4 * 4) = h;
    }
    __syncthreads();

    short8v a[8];
#pragma unroll
    for (int mt = 0; mt < 8; ++mt) {
      int d = mt * 16 + (lane & 15);
      const short* pr = P_lds + d * 136 + es * 32 + ((lane >> 4) << 2);
      a[mt] = cat8(*(const short4v*)pr, *(const short4v*)(pr + 16));
    }
#pragma unroll
    for (int nl = 0; nl < 2; ++nl) {
      int srow = (wv * 2 + nl) * 16 + (lane & 15);
      const short* vr = V_lds + srow * 36 + ((lane >> 4) << 2);
      short8v b = cat8(*(const short4v*)vr, *(const short4v*)(vr + 16));
#pragma unroll
      for (int mt = 0; mt < 8; ++mt)
        acc[mt][nl] = __builtin_amdgcn_mfma_f32_16x16x32_bf16(a[mt], b, acc[mt][nl], 0, 0, 0);
    }
  }

  float* ob = out + (size_t)bh * D_ * S_ + s0;
#pragma unroll
  for (int mt = 0; mt < 8; ++mt)
#pragma unroll
    for (int nl = 0; nl < 2; ++nl) {
      int sc = (wv * 2 + nl) * 16 + (lane & 15);
#pragma unroll
      for (int r = 0; r < 4; ++r) {
        int d = mt * 16 + ((lane >> 4) << 2) + r;
        ob[(size_t)d * S_ + sc] = acc[mt][nl][r];
      }
    }
}

extern "C" void kernel_launch(void* const* d_in, const int* in_sizes, int n_in,
                              void* d_out, int out_size, void* d_ws,
                              size_t ws_size, hipStream_t stream) {
  const float* q = (const float*)d_in[0];
  const float* k = (const float*)d_in[1];
  const float* v = (const float*)d_in[2];
  float* out = (float*)d_out;
  char* ws = (char*)d_ws;

  const size_t PART1 = (size_t)BH * D_ * D_ * sizeof(float);  // 4 MiB
  const size_t PSZ = (size_t)BH * D_ * D_ * sizeof(short);    // 2 MiB

  if (ws_size >= 16 * PART1 + PSZ) {
    float* part = (float*)ws;
    short* Pg = (short*)(ws + 16 * PART1);
    qk_mfma<16, false><<<dim3(BH, 16), 256, 0, stream>>>(q, k, part);
    softmax_k<16><<<dim3(BH, 4), 256, 0, stream>>>(part, Pg);
    pv_mfma<<<dim3(BH, 32), 256, 0, stream>>>(Pg, v, out);
  } else if (ws_size >= 8 * PART1 + PSZ) {
    float* part = (float*)ws;
    short* Pg = (short*)(ws + 8 * PART1);
    qk_mfma<8, false><<<dim3(BH, 8), 256, 0, stream>>>(q, k, part);
    softmax_k<8><<<dim3(BH, 4), 256, 0, stream>>>(part, Pg);
    pv_mfma<<<dim3(BH, 32), 256, 0, stream>>>(Pg, v, out);
  } else {
    float* part = (float*)ws;
    short* Pg = (short*)(ws + PART1);
    hipMemsetAsync(ws, 0, PART1, stream);
    qk_mfma<16, true><<<dim3(BH, 16), 256, 0, stream>>>(q, k, part);
    softmax_k<1><<<dim3(BH, 4), 256, 0, stream>>>(part, Pg);
    pv_mfma<<<dim3(BH, 32), 256, 0, stream>>>(Pg, v, out);
  }
}